// Round 6
// baseline (178.768 us; speedup 1.0000x reference)
//
#include <hip/hip_runtime.h>

#define BATCH 262144
#define NBLK 512
#define NITER 32          // 8192 row-tiles * 2 col-halves / 512 blocks
#define ROWS 32           // rows per tile
#define ASTRIDE 264       // bf16 elems per LDS A-row (528B)
#define GSTRIDE 68        // f32 per gate-grid row (32 cols used + pad)
#define GPLANE (ROWS * GSTRIDE)
#define BH 33554432       // B*H

typedef __attribute__((ext_vector_type(8))) short bf16x8;
typedef __attribute__((ext_vector_type(4))) float f32x4;
typedef __attribute__((ext_vector_type(8))) unsigned short u16x8;

__device__ __forceinline__ unsigned short f2bf(float f) {
  unsigned int u = __float_as_uint(f);
  u += 0x7fffu + ((u >> 16) & 1u);  // round-to-nearest-even
  return (unsigned short)(u >> 16);
}

__device__ __forceinline__ float fexp(float x) { return __builtin_amdgcn_exp2f(x * 1.44269504f); }
__device__ __forceinline__ float sigm(float x) { return __builtin_amdgcn_rcpf(1.f + fexp(-x)); }
__device__ __forceinline__ float ftanh(float x) { return 1.f - 2.f * __builtin_amdgcn_rcpf(1.f + fexp(2.f * x)); }

// Wave split: wave = (ct, gp). ct = col-tile (16 cols), gp = gate-pair
// ({i,f} or {o,g}). Weights per lane: 2 gates x 8 kk = 64 VGPR (half of the
// 4-gate scheme) -> 4 waves/SIMD occupancy. Partial gates exchanged via Glds.
__global__ __launch_bounds__(512, 4) void lstm_fused(
    const float* __restrict__ X, const float* __restrict__ H0, const float* __restrict__ C0,
    const float* __restrict__ Wii, const float* __restrict__ Whi,
    const float* __restrict__ Wif, const float* __restrict__ Whf,
    const float* __restrict__ Wio, const float* __restrict__ Who,
    const float* __restrict__ Wig, const float* __restrict__ Whg,
    float* __restrict__ Out) {
  __shared__ __align__(16) unsigned short Abuf[2][ROWS * ASTRIDE];
  __shared__ __align__(16) float Glds[4 * GPLANE];

  const int tid = threadIdx.x;
  const int wave = tid >> 6;
  const int lane = tid & 63;
  const int lrow = lane & 15;
  const int lkq = lane >> 4;       // k quarter (0..3)
  const int ct = wave & 3;         // col-tile within the 64-col half
  const int gp = wave >> 2;        // gate pair: 0 -> {i,f}, 1 -> {o,g}

  // XCD pairing: blocks {bid, bid+8} have the same bid&7 (same XCD) and cover
  // the two col-halves of the same row-tile -> shared X/H hits that XCD's L2.
  const int bid = blockIdx.x;
  const int xcd = bid & 7;
  const int ch = (bid >> 3) & 1;   // col half
  const int p = bid >> 4;          // 0..31
  const int tbase = p + 32 * xcd;  // tile = tbase + 256*it
  const int col0 = ch * 64;

  const int hcol = col0 + ct * 16 + lrow;  // hidden col for weight fragments

  const float* Wxp[4] = {Wii, Wif, Wio, Wig};
  const float* Whp[4] = {Whi, Whf, Who, Whg};

  // ---- weight fragments: 2 gates x 8 K-tiles, resident all kernel ----
  bf16x8 wf[2][8];
#pragma unroll
  for (int gg = 0; gg < 2; ++gg) {
    const int g = gp * 2 + gg;
#pragma unroll
    for (int kk = 0; kk < 8; ++kk) {
      const int k = kk * 32 + lkq * 8;
      const float* src = (kk < 4) ? (Wxp[g] + hcol * 128 + k)
                                  : (Whp[g] + hcol * 128 + (k - 128));
      float4 lo = *(const float4*)src;
      float4 hi = *(const float4*)(src + 4);
      bf16x8 w;
      w[0] = (short)f2bf(lo.x); w[1] = (short)f2bf(lo.y);
      w[2] = (short)f2bf(lo.z); w[3] = (short)f2bf(lo.w);
      w[4] = (short)f2bf(hi.x); w[5] = (short)f2bf(hi.y);
      w[6] = (short)f2bf(hi.z); w[7] = (short)f2bf(hi.w);
      wf[gg][kk] = w;
    }
  }

  // ---- staging: 512 thr cover 32 rows x 256 cols f32; 16 thr/row x 16 f32 ----
  const int r0 = tid >> 4;         // 0..31
  const int ci = tid & 15;         // 16-float chunk: ci<8 -> X, else H
  float4 s0, s1, s2, s3;
  float cva[4];                    // C_prev, statically indexed only

#define ISSUE_LOADS(ROW0) do {                                            \
    const float* b_ = (ci < 8)                                            \
        ? (X + (size_t)((ROW0) + r0) * 128 + ci * 16)                     \
        : (H0 + (size_t)((ROW0) + r0) * 128 + (ci - 8) * 16);             \
    s0 = ((const float4*)b_)[0];  s1 = ((const float4*)b_)[1];            \
    s2 = ((const float4*)b_)[2];  s3 = ((const float4*)b_)[3];            \
  } while (0)

#define ISSUE_CV(ROW0) do {                                               \
    _Pragma("unroll")                                                     \
    for (int j_ = 0; j_ < 4; ++j_)                                        \
      cva[j_] = C0[(size_t)((ROW0) + 4 * wave + j_) * 128 + col0 + lane]; \
  } while (0)

#define CVT8(DST, A, B) do {                                              \
    u16x8 t_;                                                             \
    t_[0] = f2bf((A).x); t_[1] = f2bf((A).y);                             \
    t_[2] = f2bf((A).z); t_[3] = f2bf((A).w);                             \
    t_[4] = f2bf((B).x); t_[5] = f2bf((B).y);                             \
    t_[6] = f2bf((B).z); t_[7] = f2bf((B).w);                             \
    *(u16x8*)(DST) = t_;                                                  \
  } while (0)

#define BODY(IT, AB) do {                                                 \
    const int row0_ = (tbase + (IT) * 256) * ROWS;                        \
    /* staged regs -> LDS bf16 */                                         \
    CVT8(&(AB)[r0 * ASTRIDE + ci * 16], s0, s1);                          \
    CVT8(&(AB)[r0 * ASTRIDE + ci * 16 + 8], s2, s3);                      \
    __syncthreads();  /* B1: A ready; prev epilogue's Glds reads done */  \
    ISSUE_CV(row0_);  /* needed after B2; in flight across MFMA */        \
    /* MFMA: 2 row-tiles x 8 kk x 2 gates */                              \
    f32x4 a00 = {0.f, 0.f, 0.f, 0.f}, a01 = a00, a10 = a00, a11 = a00;    \
    _Pragma("unroll")                                                     \
    for (int kk = 0; kk < 8; ++kk) {                                      \
      bf16x8 aA = *(const bf16x8*)&(AB)[lrow * ASTRIDE + kk * 32 + lkq * 8];        \
      bf16x8 aB = *(const bf16x8*)&(AB)[(16 + lrow) * ASTRIDE + kk * 32 + lkq * 8]; \
      a00 = __builtin_amdgcn_mfma_f32_16x16x32_bf16(aA, wf[0][kk], a00, 0, 0, 0);   \
      a01 = __builtin_amdgcn_mfma_f32_16x16x32_bf16(aA, wf[1][kk], a01, 0, 0, 0);   \
      a10 = __builtin_amdgcn_mfma_f32_16x16x32_bf16(aB, wf[0][kk], a10, 0, 0, 0);   \
      a11 = __builtin_amdgcn_mfma_f32_16x16x32_bf16(aB, wf[1][kk], a11, 0, 0, 0);   \
    }                                                                     \
    /* partial gate grids -> Glds */                                      \
    _Pragma("unroll")                                                     \
    for (int j_ = 0; j_ < 4; ++j_) {                                      \
      const int gr = (lkq * 4 + j_) * GSTRIDE + ct * 16 + lrow;           \
      Glds[(gp * 2 + 0) * GPLANE + gr] = a00[j_];                         \
      Glds[(gp * 2 + 1) * GPLANE + gr] = a01[j_];                         \
      Glds[(gp * 2 + 0) * GPLANE + 16 * GSTRIDE + gr] = a10[j_];          \
      Glds[(gp * 2 + 1) * GPLANE + 16 * GSTRIDE + gr] = a11[j_];          \
    }                                                                     \
    __syncthreads();  /* B2: all 4 gates visible */                       \
    /* next tile's X/H: in flight across the epilogue below */            \
    if ((IT) + 1 < NITER) ISSUE_LOADS(row0_ + 256 * ROWS);                \
    /* epilogue: wave -> rows [4w,4w+4), lane -> col (256B-coalesced) */  \
    _Pragma("unroll")                                                     \
    for (int j_ = 0; j_ < 4; ++j_) {                                      \
      const int rl = 4 * wave + j_;                                       \
      const float gi = Glds[0 * GPLANE + rl * GSTRIDE + lane];            \
      const float gf = Glds[1 * GPLANE + rl * GSTRIDE + lane];            \
      const float go = Glds[2 * GPLANE + rl * GSTRIDE + lane];            \
      const float gc = Glds[3 * GPLANE + rl * GSTRIDE + lane];            \
      const float itv = sigm(gi);                                         \
      const float ftv = sigm(gf);                                         \
      const float otv = sigm(go);                                         \
      const float gtv = ftanh(gc);                                        \
      const float ctv = ftv * cva[j_] + itv * gtv;                        \
      const float htv = otv * ftanh(ctv);                                 \
      const size_t o_ = (size_t)(row0_ + rl) * 128 + col0 + lane;         \
      Out[o_] = htv;                                                      \
      Out[BH + o_] = ctv;                                                 \
    }                                                                     \
  } while (0)

  // ---- prologue: prefetch tile 0's X/H ----
  ISSUE_LOADS(tbase * ROWS);

  // unroll-by-2: A-buffer parity compile-time
  for (int it = 0; it < NITER; it += 2) {
    BODY(it, &Abuf[0][0]);
    BODY(it + 1, &Abuf[1][0]);
  }

#undef ISSUE_LOADS
#undef ISSUE_CV
#undef CVT8
#undef BODY
}

extern "C" void kernel_launch(void* const* d_in, const int* in_sizes, int n_in,
                              void* d_out, int out_size, void* d_ws, size_t ws_size,
                              hipStream_t stream) {
  (void)in_sizes; (void)n_in; (void)out_size; (void)d_ws; (void)ws_size;
  lstm_fused<<<NBLK, 512, 0, stream>>>(
      (const float*)d_in[0], (const float*)d_in[1], (const float*)d_in[2],
      (const float*)d_in[3], (const float*)d_in[4], (const float*)d_in[5],
      (const float*)d_in[6], (const float*)d_in[7], (const float*)d_in[8],
      (const float*)d_in[9], (const float*)d_in[10],
      (float*)d_out);
}

// Round 7
// 166.517 us; speedup vs baseline: 1.0736x; 1.0736x over previous
//
#include <hip/hip_runtime.h>

#define BATCH 262144
#define NBLK 512
#define NITER 32          // 8192 row-tiles * 2 col-halves / 512 blocks
#define ROWS 32           // rows per tile
#define ASTRIDE 264       // bf16 elems per LDS A-row (528B)
#define BH 33554432       // B*H

typedef __attribute__((ext_vector_type(8))) short bf16x8;
typedef __attribute__((ext_vector_type(4))) float f32x4;
typedef __attribute__((ext_vector_type(8))) unsigned short u16x8;

__device__ __forceinline__ unsigned short f2bf(float f) {
  unsigned int u = __float_as_uint(f);
  u += 0x7fffu + ((u >> 16) & 1u);  // round-to-nearest-even
  return (unsigned short)(u >> 16);
}

__device__ __forceinline__ float fexp(float x) { return __builtin_amdgcn_exp2f(x * 1.44269504f); }
__device__ __forceinline__ float sigm(float x) { return __builtin_amdgcn_rcpf(1.f + fexp(-x)); }
__device__ __forceinline__ float ftanh(float x) { return 1.f - 2.f * __builtin_amdgcn_rcpf(1.f + fexp(2.f * x)); }

// 256-thread blocks (4 waves) -> two independent barrier domains per CU.
// Wave = 16-col tile, all 4 gates (weights resident: 128 VGPR/lane).
// MFMA operands SWAPPED (weights as arg0): D row-index = weight col, so each
// lane owns 4 consecutive output cols of one batch row -> dwordx4 stores/loads.
__global__ __launch_bounds__(256, 2) void lstm_fused(
    const float* __restrict__ X, const float* __restrict__ H0, const float* __restrict__ C0,
    const float* __restrict__ Wii, const float* __restrict__ Whi,
    const float* __restrict__ Wif, const float* __restrict__ Whf,
    const float* __restrict__ Wio, const float* __restrict__ Who,
    const float* __restrict__ Wig, const float* __restrict__ Whg,
    float* __restrict__ Out) {
  __shared__ __align__(16) unsigned short Abuf[2][ROWS * ASTRIDE];

  const int tid = threadIdx.x;
  const int wave = tid >> 6;       // 0..3: col-tile
  const int lane = tid & 63;
  const int lrow = lane & 15;      // batch row within 16-row MFMA tile
  const int lkq = lane >> 4;       // k quarter / output col quarter

  // XCD pairing: blocks {bid, bid+8} share bid&7 (same XCD) and cover the two
  // col-halves of the same row-tile set -> duplicated X/H reads hit that L2.
  const int bid = blockIdx.x;
  const int xcd = bid & 7;
  const int ch = (bid >> 3) & 1;   // col half
  const int p = bid >> 4;          // 0..31
  const int tbase = p + 32 * xcd;  // tile = tbase + 256*it
  const int colbase = ch * 64 + wave * 16;
  const int hcol = colbase + lrow; // weight col for fragment loads

  const float* Wxp[4] = {Wii, Wif, Wio, Wig};
  const float* Whp[4] = {Whi, Whf, Who, Whg};

  // ---- weight fragments: 4 gates x 8 K-tiles, resident all kernel ----
  bf16x8 wf[4][8];
#pragma unroll
  for (int g = 0; g < 4; ++g) {
#pragma unroll
    for (int kk = 0; kk < 8; ++kk) {
      const int k = kk * 32 + lkq * 8;
      const float* src = (kk < 4) ? (Wxp[g] + hcol * 128 + k)
                                  : (Whp[g] + hcol * 128 + (k - 128));
      float4 lo = *(const float4*)src;
      float4 hi = *(const float4*)(src + 4);
      bf16x8 w;
      w[0] = (short)f2bf(lo.x); w[1] = (short)f2bf(lo.y);
      w[2] = (short)f2bf(lo.z); w[3] = (short)f2bf(lo.w);
      w[4] = (short)f2bf(hi.x); w[5] = (short)f2bf(hi.y);
      w[6] = (short)f2bf(hi.z); w[7] = (short)f2bf(hi.w);
      wf[g][kk] = w;
    }
  }

  // ---- staging: 256 thr cover 32 rows x 256 K-f32; thread -> rows {r0, r0+16} ----
  const int r0 = tid >> 4;         // 0..15
  const int ci = tid & 15;         // 16-f32 chunk; ci<8 -> X, else H
  const int coff = ci * 16;        // bf16 offset in LDS row (same formula both cases)
  float4 s0, s1, s2, s3, s4, s5, s6, s7;
  f32x4 cv0, cv1;                  // C_prev for mt=0/1 (dwordx4, nontemporal)

#define ISSUE_LOADS(ROW0) do {                                            \
    const float* pA_ = (ci < 8)                                           \
        ? (X + (size_t)((ROW0) + r0) * 128 + ci * 16)                     \
        : (H0 + (size_t)((ROW0) + r0) * 128 + (ci - 8) * 16);             \
    s0 = ((const float4*)pA_)[0];  s1 = ((const float4*)pA_)[1];          \
    s2 = ((const float4*)pA_)[2];  s3 = ((const float4*)pA_)[3];          \
    const float* pB_ = pA_ + 16 * 128;                                    \
    s4 = ((const float4*)pB_)[0];  s5 = ((const float4*)pB_)[1];          \
    s6 = ((const float4*)pB_)[2];  s7 = ((const float4*)pB_)[3];          \
  } while (0)

#define CVT8(DST, A, B) do {                                              \
    u16x8 t_;                                                             \
    t_[0] = f2bf((A).x); t_[1] = f2bf((A).y);                             \
    t_[2] = f2bf((A).z); t_[3] = f2bf((A).w);                             \
    t_[4] = f2bf((B).x); t_[5] = f2bf((B).y);                             \
    t_[6] = f2bf((B).z); t_[7] = f2bf((B).w);                             \
    *(u16x8*)(DST) = t_;                                                  \
  } while (0)

  // One 16-row M-tile: 8 MFMAs x 4 gates (swapped operands), fused epilogue.
#define MT(MT_, CV, AB, ROW0) do {                                        \
    f32x4 a0 = {0.f, 0.f, 0.f, 0.f}, a1 = a0, a2 = a0, a3 = a0;           \
    _Pragma("unroll")                                                     \
    for (int kk = 0; kk < 8; ++kk) {                                      \
      bf16x8 b_ = *(const bf16x8*)&(AB)[((MT_)*16 + lrow) * ASTRIDE + kk * 32 + lkq * 8]; \
      a0 = __builtin_amdgcn_mfma_f32_16x16x32_bf16(wf[0][kk], b_, a0, 0, 0, 0); \
      a1 = __builtin_amdgcn_mfma_f32_16x16x32_bf16(wf[1][kk], b_, a1, 0, 0, 0); \
      a2 = __builtin_amdgcn_mfma_f32_16x16x32_bf16(wf[2][kk], b_, a2, 0, 0, 0); \
      a3 = __builtin_amdgcn_mfma_f32_16x16x32_bf16(wf[3][kk], b_, a3, 0, 0, 0); \
    }                                                                     \
    f32x4 hv_, cf_;                                                       \
    _Pragma("unroll")                                                     \
    for (int j = 0; j < 4; ++j) {                                         \
      const float itv = sigm(a0[j]);                                      \
      const float ftv = sigm(a1[j]);                                      \
      const float otv = sigm(a2[j]);                                      \
      const float gtv = ftanh(a3[j]);                                     \
      const float ctv = ftv * (CV)[j] + itv * gtv;                        \
      cf_[j] = ctv;                                                       \
      hv_[j] = otv * ftanh(ctv);                                          \
    }                                                                     \
    const size_t ob_ = (size_t)((ROW0) + (MT_)*16 + lrow) * 128 + colbase + lkq * 4; \
    __builtin_nontemporal_store(hv_, (f32x4*)(Out + ob_));                \
    __builtin_nontemporal_store(cf_, (f32x4*)(Out + BH + ob_));           \
  } while (0)

#define BODY(IT, AB) do {                                                 \
    const int row0_ = (tbase + (IT) * 256) * ROWS;                        \
    /* staged regs -> LDS bf16 (4x ds_write_b128) */                      \
    CVT8(&(AB)[r0 * ASTRIDE + coff], s0, s1);                             \
    CVT8(&(AB)[r0 * ASTRIDE + coff + 8], s2, s3);                         \
    CVT8(&(AB)[(r0 + 16) * ASTRIDE + coff], s4, s5);                      \
    CVT8(&(AB)[(r0 + 16) * ASTRIDE + coff + 8], s6, s7);                  \
    __syncthreads();  /* single barrier per iter (double buffer) */       \
    /* C_prev (nt, dwordx4) first: oldest in vmcnt FIFO, consumed in */   \
    /* the epilogues below; then next tile's X/H -> in flight across */   \
    /* the whole compute window */                                        \
    cv0 = __builtin_nontemporal_load(                                     \
        (const f32x4*)(C0 + (size_t)(row0_ + lrow) * 128 + colbase + lkq * 4));      \
    cv1 = __builtin_nontemporal_load(                                     \
        (const f32x4*)(C0 + (size_t)(row0_ + 16 + lrow) * 128 + colbase + lkq * 4)); \
    if ((IT) + 1 < NITER) ISSUE_LOADS(row0_ + 256 * ROWS);                \
    MT(0, cv0, AB, row0_);                                                \
    MT(1, cv1, AB, row0_);                                                \
  } while (0)

  // ---- prologue: prefetch tile 0's X/H ----
  ISSUE_LOADS(tbase * ROWS);

  // unroll-by-2: A-buffer parity compile-time
  for (int it = 0; it < NITER; it += 2) {
    BODY(it, &Abuf[0][0]);
    BODY(it + 1, &Abuf[1][0]);
  }

#undef ISSUE_LOADS
#undef CVT8
#undef MT
#undef BODY
}

extern "C" void kernel_launch(void* const* d_in, const int* in_sizes, int n_in,
                              void* d_out, int out_size, void* d_ws, size_t ws_size,
                              hipStream_t stream) {
  (void)in_sizes; (void)n_in; (void)out_size; (void)d_ws; (void)ws_size;
  lstm_fused<<<NBLK, 256, 0, stream>>>(
      (const float*)d_in[0], (const float*)d_in[1], (const float*)d_in[2],
      (const float*)d_in[3], (const float*)d_in[4], (const float*)d_in[5],
      (const float*)d_in[6], (const float*)d_in[7], (const float*)d_in[8],
      (const float*)d_in[9], (const float*)d_in[10],
      (float*)d_out);
}